// Round 17
// baseline (80.561 us; speedup 1.0000x reference)
//
#include <hip/hip_runtime.h>
#include <hip/hip_bf16.h>
#include <math.h>

#define N_IN 28
#define N_MID 256
#define N_OUT 28
#define SEQ 28
#define BATCH 4096
#define G3 768
#define ROWS 16
#define THREADS 512
#define NBLK (BATCH / ROWS)   // 256

#define LOG2E  1.44269504f
#define LOG2E2 2.88539008f

typedef __attribute__((ext_vector_type(8))) short bf16x8;
typedef __attribute__((ext_vector_type(4))) float f32x4;

#define MFMA(a, b, c) __builtin_amdgcn_mfma_f32_16x16x32_bf16((a), (b), (c), 0, 0, 0)

__device__ __forceinline__ f32x4 splat4(float v) {
    f32x4 r;
    r[0] = v; r[1] = v; r[2] = v; r[3] = v;
    return r;
}

__device__ __forceinline__ short f2bf(float v) {          // RNE (prep kernels)
    __hip_bfloat16 b = __float2bfloat16(v);
    return *reinterpret_cast<short*>(&b);
}
__device__ __forceinline__ float bf2f(short s) {
    unsigned int u = ((unsigned int)(unsigned short)s) << 16;
    return __uint_as_float(u);
}
// HW packed f32->bf16 RNE: lo16 = bf16(a), hi16 = bf16(b)
__device__ __forceinline__ unsigned cvt_pk_bf16(float a, float b) {
    unsigned d;
    asm("v_cvt_pk_bf16_f32 %0, %1, %2" : "=v"(d) : "v"(a), "v"(b));
    return d;
}
__device__ __forceinline__ float frcp(float v) {          // raw v_rcp_f32
    return __builtin_amdgcn_rcpf(v);
}
__device__ __forceinline__ float fexp2(float v) {         // raw v_exp_f32 (2^x)
#if __has_builtin(__builtin_amdgcn_exp2f)
    return __builtin_amdgcn_exp2f(v);
#else
    return __expf(v * 0.69314718f);
#endif
}
// pre-activations arrive pre-scaled by log2e (R,Z) / 2*log2e (N) via weights
__device__ __forceinline__ float fsigmoid2(float v) {     // v = log2e * act
    return frcp(1.0f + fexp2(-v));
}
__device__ __forceinline__ float ftanh2(float v) {        // v = 2*log2e * act
    return fmaf(-2.0f, frcp(1.0f + fexp2(v)), 1.0f);
}

// prep: w_hh -> wB bf16 (rows prescaled: R/Z x log2e, N x 2log2e);
// w_ih -> wI bf16 [768][32], same prescale, k=28/29 = scaled bias hi/lo.
__global__ void prep_w(const float* __restrict__ w_hh, const float* __restrict__ w_ih,
                       const float* __restrict__ b_ih, const float* __restrict__ b_hh,
                       short* __restrict__ wB, short* __restrict__ wI) {
    int idx = blockIdx.x * 256 + threadIdx.x;
    if (idx < G3 * N_MID) {
        int g = idx >> 8;
        float s = (g < 2 * N_MID) ? LOG2E : LOG2E2;
        wB[idx] = f2bf(w_hh[idx] * s);
    }
    if (idx < G3 * 32) {
        int g = idx >> 5, k = idx & 31;
        float s = (g < 2 * N_MID) ? LOG2E : LOG2E2;
        float v = 0.0f;
        if (k < N_IN) {
            v = w_ih[g * N_IN + k] * s;
        } else if (k == 28 || k == 29) {
            float bias = ((g < 2 * N_MID) ? (b_ih[g] + b_hh[g]) : b_ih[g]) * s;
            v = (k == 28) ? bias : (bias - bf2f(f2bf(bias)));
        }
        wI[idx] = f2bf(v);
    }
}

// prep: x [B][T][28] f32 -> xbf [T][B][32] bf16, k=28/29 = 1.0 (bias carriers),
// k=30/31 = 0. One-time; per-step x-load becomes a single 16B A-fragment read.
__global__ void prep_x(const float* __restrict__ x, short* __restrict__ xbf) {
    int idx = blockIdx.x * 256 + threadIdx.x;
    if (idx >= SEQ * BATCH * 32) return;
    int k  = idx & 31;
    int tb = idx >> 5;
    int t  = tb >> 12;           // BATCH = 4096 = 2^12
    int b  = tb & (BATCH - 1);
    float v;
    if (k < N_IN)            v = x[(size_t)b * (SEQ * N_IN) + t * N_IN + k];
    else if (k == 28 || k == 29) v = 1.0f;
    else                     v = 0.0f;
    xbf[idx] = f2bf(v);
}

// One timestep. RB = read buffer, writes RB^1. HID=false: t=0 (h=0).
// xh holds x(t)'s A-fragment (prefetched); this step prefetches x(t+1).
// x-proj first (independent of hl) to cover ds_read latency; acc init free
// via MFMA C-operand. K-slices 0..5 reg-resident, 6,7 from LDS (ord first).
template<bool HID, int RB, bool LAST>
__device__ __forceinline__ void gru_step(
    int t, const short* __restrict__ xbf, int rowbase,
    int l15, int lg, int wv, int lane,
    short (&hl)[2][32][17][8],
    const short (&wlds)[2][3][16][64][8],
    const bf16x8 (&wreg)[3][2][6],
    const bf16x8 (&wireg)[3][2],
    const float (&bHN)[2],
    float (&hold)[2][4], const int (&colA)[2],
    bf16x8 &xh)
{
    constexpr int WB = RB ^ 1;

    // ---- prefetch x(t+1) A-fragment; consumed NEXT step
    bf16x8 nxh;
    if (!LAST)
        nxh = *(const bf16x8*)(xbf +
              ((size_t)(t + 1) * BATCH + rowbase + l15) * 32 + lg * 8);

    const f32x4 zero4 = splat4(0.0f);
    f32x4 aR[2], aZ[2], aIN[2], aHN[2];

    // first h A-fragment read issues before the x-proj MFMAs (latency overlap)
    constexpr int ord[8] = {6, 7, 0, 1, 2, 3, 4, 5};
    bf16x8 ah2[2];
    if constexpr (HID)
        ah2[0] = *(const bf16x8*)&hl[RB][ord[0] * 4 + lg][l15][0];

    // ---- x(t) input projection (register-only inputs; C-operand init)
    #pragma unroll
    for (int a = 0; a < 2; ++a) {
        aR[a]  = MFMA(xh, wireg[0][a], zero4);
        aZ[a]  = MFMA(xh, wireg[1][a], zero4);
        aIN[a] = MFMA(xh, wireg[2][a], zero4);
        if constexpr (!HID) aHN[a] = splat4(bHN[a]);
    }

    if constexpr (HID) {
        __builtin_amdgcn_s_setprio(1);
        #pragma unroll
        for (int i = 0; i < 8; ++i) {
            const int ks = ord[i];
            const int cur = i & 1, nxt = cur ^ 1;
            if (i < 7)
                ah2[nxt] = *(const bf16x8*)&hl[RB][ord[i + 1] * 4 + lg][l15][0];
            #pragma unroll
            for (int a = 0; a < 2; ++a) {
                bf16x8 b0, b1, b2;
                if (ks < 6) {
                    b0 = wreg[0][a][ks]; b1 = wreg[1][a][ks]; b2 = wreg[2][a][ks];
                } else {
                    const int cg = 2 * wv + a;
                    b0 = *(const bf16x8*)&wlds[ks - 6][0][cg][lane][0];
                    b1 = *(const bf16x8*)&wlds[ks - 6][1][cg][lane][0];
                    b2 = *(const bf16x8*)&wlds[ks - 6][2][cg][lane][0];
                }
                aR[a] = MFMA(ah2[cur], b0, aR[a]);
                aZ[a] = MFMA(ah2[cur], b1, aZ[a]);
                if (i == 0) {   // C-operand supplies bHN init
                    aHN[a] = MFMA(ah2[cur], b2, splat4(bHN[a]));
                } else {
                    aHN[a] = MFMA(ah2[cur], b2, aHN[a]);
                }
            }
        }
        __builtin_amdgcn_s_setprio(0);
    }

    // ---- lane-local GRU update; write h(t+1) A-fragments (packed HW converts)
    #pragma unroll
    for (int a = 0; a < 2; ++a) {
        const int c = colA[a];
        float hn4[4];
        #pragma unroll
        for (int j = 0; j < 4; ++j) {
            float r = fsigmoid2(aR[a][j]);
            float z = fsigmoid2(aZ[a][j]);
            float n = ftanh2(aIN[a][j] + r * aHN[a][j]);
            float hnew = fmaf(z, hold[a][j] - n, n);
            hold[a][j] = hnew;
            hn4[j] = hnew;
        }
        unsigned p01 = cvt_pk_bf16(hn4[0], hn4[1]);
        unsigned p23 = cvt_pk_bf16(hn4[2], hn4[3]);
        short* bp = &hl[WB][c >> 3][4 * lg][c & 7];   // row stride = 8 shorts
        bp[0]  = (short)(p01 & 0xffffu);
        bp[8]  = (short)(p01 >> 16);
        bp[16] = (short)(p23 & 0xffffu);
        bp[24] = (short)(p23 >> 16);
    }

    if (!LAST) xh = nxh;   // rotate prefetch
    __syncthreads();
}

__global__ __launch_bounds__(THREADS, 2) void gru_onecu(
    const short* __restrict__ xbf,   // [T][B][32] bf16 (k28/29 = 1.0 carriers)
    const short* __restrict__ wB,    // [768][256] bf16 (log2e-prescaled)
    const short* __restrict__ wI,    // [768][32] bf16 (prescaled, k28/29 bias)
    const float* __restrict__ b_hh,
    const float* __restrict__ fc_w,  // [28][256]
    const float* __restrict__ fc_b,
    float* __restrict__ out)         // [B][28]
{
    // Weight K-slices 6,7 as frag-linear B-fragments (96 KB)
    __shared__ short wlds[2][3][16][64][8];
    // h double-buffer A-fragments, single bf16 (17 KB)
    __shared__ short hl[2][32][17][8];

    const int tid  = threadIdx.x;
    const int lane = tid & 63;
    const int l15  = lane & 15;
    const int lg   = lane >> 4;
    const int wv   = tid >> 6;              // wave owns cols [32wv, 32wv+32)
    const int rowbase = blockIdx.x * ROWS;

    // ---- one-time: stage K-slices 6,7 into LDS (frag-linear, conflict-free)
    for (int idx = tid; idx < 2 * 3 * 16 * 64; idx += THREADS) {
        int L    = idx & 63;
        int frag = idx >> 6;
        int ksl  = frag / 48;
        int rem  = frag - ksl * 48;
        int g    = rem >> 4;
        int cg   = rem & 15;
        int col  = cg * 16 + (L & 15);
        int k0   = (6 + ksl) * 32 + (L >> 4) * 8;
        *(bf16x8*)&wlds[ksl][g][cg][L][0] =
            *(const bf16x8*)(wB + ((size_t)(g * 256 + col)) * 256 + k0);
    }

    // ---- one-time: K-slices 0..5 + w_ih into registers, bHN scalars (scaled)
    bf16x8 wreg[3][2][6];
    bf16x8 wireg[3][2];
    int   colA[2];
    float bHN[2];
    #pragma unroll
    for (int a = 0; a < 2; ++a) {
        const int c = wv * 32 + a * 16 + l15;
        colA[a] = c;
        bHN[a]  = b_hh[512 + c] * LOG2E2;
        #pragma unroll
        for (int g = 0; g < 3; ++g) {
            wireg[g][a] = *(const bf16x8*)(wI + ((size_t)(g * 256 + c)) * 32 + lg * 8);
            #pragma unroll
            for (int ks = 0; ks < 6; ++ks)
                wreg[g][a][ks] =
                    *(const bf16x8*)(wB + ((size_t)(g * 256 + c)) * 256 + ks * 32 + lg * 8);
        }
    }

    float hold[2][4] = {};

    // ---- prologue x(0) A-fragment load
    bf16x8 xh = *(const bf16x8*)(xbf + ((size_t)(rowbase + l15)) * 32 + lg * 8);

    __syncthreads();

    // t=0 (h=0) writes buf1; pairs keep compile-time buffer indices
    gru_step<false, 0, false>(0, xbf, rowbase, l15, lg, wv, lane, hl, wlds, wreg,
                              wireg, bHN, hold, colA, xh);
    for (int tt = 1; tt < SEQ - 1; tt += 2) {
        gru_step<true, 1, false>(tt, xbf, rowbase, l15, lg, wv, lane, hl, wlds,
                                 wreg, wireg, bHN, hold, colA, xh);
        gru_step<true, 0, false>(tt + 1, xbf, rowbase, l15, lg, wv, lane, hl, wlds,
                                 wreg, wireg, bHN, hold, colA, xh);
    }
    gru_step<true, 1, true>(SEQ - 1, xbf, rowbase, l15, lg, wv, lane, hl, wlds,
                            wreg, wireg, bHN, hold, colA, xh);

    // ---- FC epilogue: h(SEQ) in buf0
    float* hf = (float*)&wlds[0][0][0][0][0];   // overlay 16 KB on weight LDS
    {
        int r = tid >> 5, kg = tid & 31;
        #pragma unroll
        for (int e = 0; e < 8; ++e) {
            int k = kg * 8 + e;
            hf[r * 256 + k] = bf2f(hl[0][k >> 3][r][k & 7]);
        }
    }
    __syncthreads();
    if (tid < ROWS * N_OUT) {
        int r = tid / N_OUT, o = tid - r * N_OUT;
        float acc = fc_b[o];
        #pragma unroll
        for (int k4 = 0; k4 < 64; ++k4) {
            float4 hv = *(const float4*)&hf[r * 256 + k4 * 4];
            float4 wv4 = *(const float4*)&fc_w[o * 256 + k4 * 4];
            acc = fmaf(hv.x, wv4.x, acc);
            acc = fmaf(hv.y, wv4.y, acc);
            acc = fmaf(hv.z, wv4.z, acc);
            acc = fmaf(hv.w, wv4.w, acc);
        }
        out[(size_t)(rowbase + r) * N_OUT + o] = acc;
    }
}

extern "C" void kernel_launch(void* const* d_in, const int* in_sizes, int n_in,
                              void* d_out, int out_size, void* d_ws, size_t ws_size,
                              hipStream_t stream) {
    const float* x    = (const float*)d_in[0];
    const float* w_ih = (const float*)d_in[1];
    const float* w_hh = (const float*)d_in[2];
    const float* b_ih = (const float*)d_in[3];
    const float* b_hh = (const float*)d_in[4];
    const float* fc_w = (const float*)d_in[5];
    const float* fc_b = (const float*)d_in[6];
    float* out = (float*)d_out;

    short* wB  = (short*)d_ws;                    // [768][256] = 384 KB
    short* wI  = wB + G3 * N_MID;                 // [768][32]  =  48 KB
    short* xbf = wI + G3 * 32;                    // [28][4096][32] = 7.34 MB

    hipLaunchKernelGGL(prep_w, dim3(768), dim3(256), 0, stream,
                       w_hh, w_ih, b_ih, b_hh, wB, wI);
    hipLaunchKernelGGL(prep_x, dim3((SEQ * BATCH * 32 + 255) / 256), dim3(256),
                       0, stream, x, xbf);
    hipLaunchKernelGGL(gru_onecu, dim3(NBLK), dim3(THREADS), 0, stream,
                       xbf, wB, wI, b_hh, fc_w, fc_b, out);
}

// Round 18
// 75.726 us; speedup vs baseline: 1.0638x; 1.0638x over previous
//
#include <hip/hip_runtime.h>
#include <hip/hip_bf16.h>
#include <math.h>

#define N_IN 28
#define N_MID 256
#define N_OUT 28
#define SEQ 28
#define BATCH 4096
#define G3 768
#define ROWS 16
#define THREADS 512
#define NBLK (BATCH / ROWS)   // 256

#define LOG2E  1.44269504f
#define LOG2E2 2.88539008f

typedef __attribute__((ext_vector_type(8))) short bf16x8;
typedef __attribute__((ext_vector_type(4))) float f32x4;

#define MFMA(a, b, c) __builtin_amdgcn_mfma_f32_16x16x32_bf16((a), (b), (c), 0, 0, 0)

__device__ __forceinline__ f32x4 splat4(float v) {
    f32x4 r;
    r[0] = v; r[1] = v; r[2] = v; r[3] = v;
    return r;
}

__device__ __forceinline__ short f2bf(float v) {          // RNE (prep kernel)
    __hip_bfloat16 b = __float2bfloat16(v);
    return *reinterpret_cast<short*>(&b);
}
__device__ __forceinline__ float bf2f(short s) {
    unsigned int u = ((unsigned int)(unsigned short)s) << 16;
    return __uint_as_float(u);
}
// HW packed f32->bf16 RNE: lo16 = bf16(a), hi16 = bf16(b)
__device__ __forceinline__ unsigned cvt_pk_bf16(float a, float b) {
    unsigned d;
    asm("v_cvt_pk_bf16_f32 %0, %1, %2" : "=v"(d) : "v"(a), "v"(b));
    return d;
}
__device__ __forceinline__ float frcp(float v) {          // raw v_rcp_f32
    return __builtin_amdgcn_rcpf(v);
}
__device__ __forceinline__ float fexp2(float v) {         // raw v_exp_f32 (2^x)
#if __has_builtin(__builtin_amdgcn_exp2f)
    return __builtin_amdgcn_exp2f(v);
#else
    return __expf(v * 0.69314718f);
#endif
}
// pre-activations arrive pre-scaled by log2e (R,Z) / 2*log2e (N) via weights
__device__ __forceinline__ float fsigmoid2(float v) {     // v = log2e * act
    return frcp(1.0f + fexp2(-v));
}
__device__ __forceinline__ float ftanh2(float v) {        // v = 2*log2e * act
    return fmaf(-2.0f, frcp(1.0f + fexp2(v)), 1.0f);
}

// prep: w_hh -> wB bf16 (rows prescaled: R/Z x log2e, N x 2log2e);
// w_ih -> wI bf16 [768][32], same prescale, k=28/29 = scaled bias hi/lo.
__global__ void prep_w(const float* __restrict__ w_hh, const float* __restrict__ w_ih,
                       const float* __restrict__ b_ih, const float* __restrict__ b_hh,
                       short* __restrict__ wB, short* __restrict__ wI) {
    int idx = blockIdx.x * 256 + threadIdx.x;
    if (idx < G3 * N_MID) {
        int g = idx >> 8;
        float s = (g < 2 * N_MID) ? LOG2E : LOG2E2;
        wB[idx] = f2bf(w_hh[idx] * s);
    }
    if (idx < G3 * 32) {
        int g = idx >> 5, k = idx & 31;
        float s = (g < 2 * N_MID) ? LOG2E : LOG2E2;
        float v = 0.0f;
        if (k < N_IN) {
            v = w_ih[g * N_IN + k] * s;
        } else if (k == 28 || k == 29) {
            float bias = ((g < 2 * N_MID) ? (b_ih[g] + b_hh[g]) : b_ih[g]) * s;
            v = (k == 28) ? bias : (bias - bf2f(f2bf(bias)));
        }
        wI[idx] = f2bf(v);
    }
}

// Convert a prefetched f32 x pair into the bf16 A-fragment (k28/29 = 1.0
// bias carriers on lg==3 lanes). Placed in the post-update shadow.
__device__ __forceinline__ bf16x8 make_xfrag(const float4 &xa, const float4 &xb,
                                             int lg) {
    unsigned w0 = cvt_pk_bf16(xa.x, xa.y);
    unsigned w1 = cvt_pk_bf16(xa.z, xa.w);
    unsigned w2 = cvt_pk_bf16(xb.x, xb.y);
    unsigned w3 = cvt_pk_bf16(xb.z, xb.w);
    if (lg == 3) w2 = 0x3F803F80u;   // bias carriers k=28,29 multiply by 1.0
    bf16x8 xh;
    unsigned* xu = (unsigned*)&xh;
    xu[0] = w0; xu[1] = w1; xu[2] = w2; xu[3] = w3;
    return xh;
}

// One timestep. RB = read buffer, writes RB^1. HID=false: t=0 (h=0).
// xh holds x(t)'s A-fragment (converted last step); prefetches+converts x(t+1).
// x-proj first (independent of hl) to cover ds_read latency; acc init free
// via MFMA C-operand. K-slices 0..5 reg-resident, 6,7 from LDS (ord first).
template<bool HID, int RB, bool LAST>
__device__ __forceinline__ void gru_step(
    int t, const float* __restrict__ x, int rowbase,
    int l15, int lg, int wv, int lane,
    short (&hl)[2][32][17][8],
    const short (&wlds)[2][3][16][64][8],
    const bf16x8 (&wreg)[3][2][6],
    const bf16x8 (&wireg)[3][2],
    const float (&bHN)[2],
    float (&hold)[2][4], const int (&colA)[2],
    bf16x8 &xh)
{
    constexpr int WB = RB ^ 1;

    // ---- prefetch x(t+1) f32; converted post-update, consumed NEXT step
    float4 nA, nB;
    if (!LAST) {
        const float* xp =
            x + (size_t)(rowbase + l15) * (SEQ * N_IN) + (t + 1) * N_IN + lg * 8;
        nA = *(const float4*)xp;
        nB.x = 0.f; nB.y = 0.f; nB.z = 0.f; nB.w = 0.f;
        if (lg < 3) nB = *(const float4*)(xp + 4);
    }

    const f32x4 zero4 = splat4(0.0f);
    f32x4 aR[2], aZ[2], aIN[2], aHN[2];

    // first h A-fragment read issues before the x-proj MFMAs (latency overlap)
    constexpr int ord[8] = {6, 7, 0, 1, 2, 3, 4, 5};
    bf16x8 ah2[2];
    if constexpr (HID)
        ah2[0] = *(const bf16x8*)&hl[RB][ord[0] * 4 + lg][l15][0];

    // ---- x(t) input projection (register-only inputs; C-operand init)
    #pragma unroll
    for (int a = 0; a < 2; ++a) {
        aR[a]  = MFMA(xh, wireg[0][a], zero4);
        aZ[a]  = MFMA(xh, wireg[1][a], zero4);
        aIN[a] = MFMA(xh, wireg[2][a], zero4);
        if constexpr (!HID) aHN[a] = splat4(bHN[a]);
    }

    if constexpr (HID) {
        __builtin_amdgcn_s_setprio(1);
        #pragma unroll
        for (int i = 0; i < 8; ++i) {
            const int ks = ord[i];
            const int cur = i & 1, nxt = cur ^ 1;
            if (i < 7)
                ah2[nxt] = *(const bf16x8*)&hl[RB][ord[i + 1] * 4 + lg][l15][0];
            #pragma unroll
            for (int a = 0; a < 2; ++a) {
                bf16x8 b0, b1, b2;
                if (ks < 6) {
                    b0 = wreg[0][a][ks]; b1 = wreg[1][a][ks]; b2 = wreg[2][a][ks];
                } else {
                    const int cg = 2 * wv + a;
                    b0 = *(const bf16x8*)&wlds[ks - 6][0][cg][lane][0];
                    b1 = *(const bf16x8*)&wlds[ks - 6][1][cg][lane][0];
                    b2 = *(const bf16x8*)&wlds[ks - 6][2][cg][lane][0];
                }
                aR[a] = MFMA(ah2[cur], b0, aR[a]);
                aZ[a] = MFMA(ah2[cur], b1, aZ[a]);
                if (i == 0) {   // C-operand supplies bHN init
                    aHN[a] = MFMA(ah2[cur], b2, splat4(bHN[a]));
                } else {
                    aHN[a] = MFMA(ah2[cur], b2, aHN[a]);
                }
            }
        }
        __builtin_amdgcn_s_setprio(0);
    }

    // ---- lane-local GRU update; write h(t+1) A-fragments (packed HW converts)
    #pragma unroll
    for (int a = 0; a < 2; ++a) {
        const int c = colA[a];
        float hn4[4];
        #pragma unroll
        for (int j = 0; j < 4; ++j) {
            float r = fsigmoid2(aR[a][j]);
            float z = fsigmoid2(aZ[a][j]);
            float n = ftanh2(aIN[a][j] + r * aHN[a][j]);
            float hnew = fmaf(z, hold[a][j] - n, n);
            hold[a][j] = hnew;
            hn4[j] = hnew;
        }
        unsigned p01 = cvt_pk_bf16(hn4[0], hn4[1]);
        unsigned p23 = cvt_pk_bf16(hn4[2], hn4[3]);
        short* bp = &hl[WB][c >> 3][4 * lg][c & 7];   // row stride = 8 shorts
        bp[0]  = (short)(p01 & 0xffffu);
        bp[8]  = (short)(p01 >> 16);
        bp[16] = (short)(p23 & 0xffffu);
        bp[24] = (short)(p23 >> 16);
    }

    // ---- post-update shadow: convert x(t+1) to its A-fragment
    if (!LAST) xh = make_xfrag(nA, nB, lg);
    __syncthreads();
}

__global__ __launch_bounds__(THREADS, 2) void gru_onecu(
    const float* __restrict__ x,     // [B][T][28]
    const short* __restrict__ wB,    // [768][256] bf16 (log2e-prescaled)
    const short* __restrict__ wI,    // [768][32] bf16 (prescaled, k28/29 bias)
    const float* __restrict__ b_hh,
    const float* __restrict__ fc_w,  // [28][256]
    const float* __restrict__ fc_b,
    float* __restrict__ out)         // [B][28]
{
    // Weight K-slices 6,7 as frag-linear B-fragments (96 KB)
    __shared__ short wlds[2][3][16][64][8];
    // h double-buffer A-fragments, single bf16 (17 KB)
    __shared__ short hl[2][32][17][8];

    const int tid  = threadIdx.x;
    const int lane = tid & 63;
    const int l15  = lane & 15;
    const int lg   = lane >> 4;
    const int wv   = tid >> 6;              // wave owns cols [32wv, 32wv+32)
    const int rowbase = blockIdx.x * ROWS;

    // ---- one-time: stage K-slices 6,7 into LDS (frag-linear, conflict-free)
    for (int idx = tid; idx < 2 * 3 * 16 * 64; idx += THREADS) {
        int L    = idx & 63;
        int frag = idx >> 6;
        int ksl  = frag / 48;
        int rem  = frag - ksl * 48;
        int g    = rem >> 4;
        int cg   = rem & 15;
        int col  = cg * 16 + (L & 15);
        int k0   = (6 + ksl) * 32 + (L >> 4) * 8;
        *(bf16x8*)&wlds[ksl][g][cg][L][0] =
            *(const bf16x8*)(wB + ((size_t)(g * 256 + col)) * 256 + k0);
    }

    // ---- one-time: K-slices 0..5 + w_ih into registers, bHN scalars (scaled)
    bf16x8 wreg[3][2][6];
    bf16x8 wireg[3][2];
    int   colA[2];
    float bHN[2];
    #pragma unroll
    for (int a = 0; a < 2; ++a) {
        const int c = wv * 32 + a * 16 + l15;
        colA[a] = c;
        bHN[a]  = b_hh[512 + c] * LOG2E2;
        #pragma unroll
        for (int g = 0; g < 3; ++g) {
            wireg[g][a] = *(const bf16x8*)(wI + ((size_t)(g * 256 + c)) * 32 + lg * 8);
            #pragma unroll
            for (int ks = 0; ks < 6; ++ks)
                wreg[g][a][ks] =
                    *(const bf16x8*)(wB + ((size_t)(g * 256 + c)) * 256 + ks * 32 + lg * 8);
        }
    }

    float hold[2][4] = {};

    // ---- prologue: load + convert x(0) A-fragment
    bf16x8 xh;
    {
        const float* xp = x + (size_t)(rowbase + l15) * (SEQ * N_IN) + lg * 8;
        float4 xa = *(const float4*)xp;
        float4 xb;
        xb.x = 0.f; xb.y = 0.f; xb.z = 0.f; xb.w = 0.f;
        if (lg < 3) xb = *(const float4*)(xp + 4);
        xh = make_xfrag(xa, xb, lg);
    }

    __syncthreads();

    // t=0 (h=0) writes buf1; pairs keep compile-time buffer indices
    gru_step<false, 0, false>(0, x, rowbase, l15, lg, wv, lane, hl, wlds, wreg,
                              wireg, bHN, hold, colA, xh);
    for (int tt = 1; tt < SEQ - 1; tt += 2) {
        gru_step<true, 1, false>(tt, x, rowbase, l15, lg, wv, lane, hl, wlds,
                                 wreg, wireg, bHN, hold, colA, xh);
        gru_step<true, 0, false>(tt + 1, x, rowbase, l15, lg, wv, lane, hl, wlds,
                                 wreg, wireg, bHN, hold, colA, xh);
    }
    gru_step<true, 1, true>(SEQ - 1, x, rowbase, l15, lg, wv, lane, hl, wlds,
                            wreg, wireg, bHN, hold, colA, xh);

    // ---- FC epilogue: h(SEQ) in buf0
    float* hf = (float*)&wlds[0][0][0][0][0];   // overlay 16 KB on weight LDS
    {
        int r = tid >> 5, kg = tid & 31;
        #pragma unroll
        for (int e = 0; e < 8; ++e) {
            int k = kg * 8 + e;
            hf[r * 256 + k] = bf2f(hl[0][k >> 3][r][k & 7]);
        }
    }
    __syncthreads();
    if (tid < ROWS * N_OUT) {
        int r = tid / N_OUT, o = tid - r * N_OUT;
        float acc = fc_b[o];
        #pragma unroll
        for (int k4 = 0; k4 < 64; ++k4) {
            float4 hv = *(const float4*)&hf[r * 256 + k4 * 4];
            float4 wv4 = *(const float4*)&fc_w[o * 256 + k4 * 4];
            acc = fmaf(hv.x, wv4.x, acc);
            acc = fmaf(hv.y, wv4.y, acc);
            acc = fmaf(hv.z, wv4.z, acc);
            acc = fmaf(hv.w, wv4.w, acc);
        }
        out[(size_t)(rowbase + r) * N_OUT + o] = acc;
    }
}

extern "C" void kernel_launch(void* const* d_in, const int* in_sizes, int n_in,
                              void* d_out, int out_size, void* d_ws, size_t ws_size,
                              hipStream_t stream) {
    const float* x    = (const float*)d_in[0];
    const float* w_ih = (const float*)d_in[1];
    const float* w_hh = (const float*)d_in[2];
    const float* b_ih = (const float*)d_in[3];
    const float* b_hh = (const float*)d_in[4];
    const float* fc_w = (const float*)d_in[5];
    const float* fc_b = (const float*)d_in[6];
    float* out = (float*)d_out;

    short* wB = (short*)d_ws;                 // [768][256] bf16 = 384 KB
    short* wI = wB + G3 * N_MID;              // [768][32]  bf16 =  48 KB

    hipLaunchKernelGGL(prep_w, dim3(768), dim3(256), 0, stream,
                       w_hh, w_ih, b_ih, b_hh, wB, wI);
    hipLaunchKernelGGL(gru_onecu, dim3(NBLK), dim3(THREADS), 0, stream,
                       x, wB, wI, b_hh, fc_w, fc_b, out);
}